// Round 13
// baseline (571.442 us; speedup 1.0000x reference)
//
#include <hip/hip_runtime.h>

// ---------------------------------------------------------------------------
// GCN: 3x GCNConv(9->16->16->16) + MLP(concat 25 ->128->128->1), N=250000,
// E=5,000,000 edges + self loops. f32 in/out; edge_index int32 OR int64
// (detected on device).
// Pipeline: deterministic 2-pass binning into 512-node buckets (single-writer
// 64B lines, zero global atomics; k_bin sentinel-fills from its scatter
// cursors -- no redundant histogram pass) -> within-bucket counting sort to
// exact CSR storing BYTE offsets (fused deg/dinv) -> per-node wave gather
// (f32 rows, 16 slots x float4, nontemporal csr reads -- bf16 rows REGRESSED
// r11: random access is billed in 64B lines and unpack doubles VALU) with
// fused 16x16 linear epilogue -> bf16 MFMA MLP head (16x16x32, fp32 acc).
// NOTE: k_mlp uses plain __launch_bounds__(256): any min-waves second arg
// makes the allocator cap at 64 VGPRs and spill the acc tile to scratch
// (observed r2/r5/r6: 190MB scratch traffic, 2-3x slowdown).
// ---------------------------------------------------------------------------

#define NBLK 512          // binning blocks (each owns a contiguous edge chunk)
#define BSH  9            // bucket shift: 512 nodes per bucket
#define BSZ  512
#define MAXNB 1024        // max buckets supported (n <= 524288)

typedef __attribute__((ext_vector_type(8))) __bf16 bf16x8;
typedef __attribute__((ext_vector_type(4))) float  f32x4;

__device__ __forceinline__ unsigned short f2b(float f)   // f32 -> bf16 RNE
{
    unsigned u = __float_as_uint(f);
    unsigned r = (u + 0x7FFFu + ((u >> 16) & 1u)) >> 16;
    return (unsigned short)r;
}

__global__ __launch_bounds__(64) void k_detect(const void* __restrict__ edges,
                                               int* __restrict__ flag, int n_nodes)
{
    if (threadIdx.x == 0 && blockIdx.x == 0) {
        const long long* p = (const long long*)edges;
        int is64 = 1;
        for (int i = 0; i < 16; ++i) {
            long long v = p[i];
            if (v < 0 || v >= (long long)n_nodes) is64 = 0;
        }
        *flag = is64;
    }
}

// little-endian: low 32 bits of int64 value < 2^31 equal the int32 value
__device__ __forceinline__ int ld_idx(const void* edges, int f64, long long idx)
{
    return f64 ? ((const int*)edges)[idx << 1] : ((const int*)edges)[idx];
}

// per-block bucket histogram of dst; write rounded-to-16 counts bucket-major.
// 2-wide vectorized reads (chunk forced even; alignment-guarded).
__global__ __launch_bounds__(256) void k_hist2(const void* __restrict__ edges,
                                               const int* __restrict__ flag,
                                               int* __restrict__ cnt_blk,
                                               long long E, long long chunk, int NB)
{
    __shared__ int cnt[MAXNB];
    int tid = threadIdx.x;
    for (int b = tid; b < NB; b += 256) cnt[b] = 0;
    __syncthreads();
    int f64 = *flag;
    long long lo = (long long)blockIdx.x * chunk;
    long long hi = lo + chunk; if (hi > E) hi = E;
    long long len = hi - lo; if (len < 0) len = 0;
    if ((E & 1) == 0) {                       // vector path (lo even by chunk)
        long long nv = len & ~1LL;
        for (long long o = (long long)tid * 2; o < nv; o += 512) {
            int d0, d1;
            if (f64) {
                longlong2 q = *(const longlong2*)((const long long*)edges + E + lo + o);
                d0 = (int)q.x; d1 = (int)q.y;
            } else {
                int2 q = *(const int2*)((const int*)edges + E + lo + o);
                d0 = q.x; d1 = q.y;
            }
            atomicAdd(&cnt[d0 >> BSH], 1);
            atomicAdd(&cnt[d1 >> BSH], 1);
        }
        if (tid == 0 && (len & 1)) {
            int d = ld_idx(edges, f64, E + hi - 1);
            atomicAdd(&cnt[d >> BSH], 1);
        }
    } else {
        for (long long i = lo + tid; i < hi; i += 256) {
            int d = ld_idx(edges, f64, E + i);
            atomicAdd(&cnt[d >> BSH], 1);
        }
    }
    __syncthreads();
    for (int b = tid; b < NB; b += 256)
        cnt_blk[(size_t)b * NBLK + blockIdx.x] = (cnt[b] + 15) & ~15;
}

// exclusive scan stage 1
__global__ __launch_bounds__(256) void k_scan1(const int* __restrict__ in,
                                               int* __restrict__ excl,
                                               int* __restrict__ partials, int n)
{
    __shared__ int s[256];
    int tid = threadIdx.x;
    int i = blockIdx.x * 256 + tid;
    int v = (i < n) ? in[i] : 0;
    s[tid] = v;
    __syncthreads();
#pragma unroll
    for (int off = 1; off < 256; off <<= 1) {
        int t = (tid >= off) ? s[tid - off] : 0;
        __syncthreads();
        s[tid] += t;
        __syncthreads();
    }
    if (i < n) excl[i] = s[tid] - v;
    if (tid == 255) partials[blockIdx.x] = s[255];
}

// stage 2: single block, exclusive scan of partials (carry loop)
__global__ __launch_bounds__(1024) void k_scan2(int* __restrict__ p, int nb)
{
    __shared__ int s[1024];
    __shared__ int carry_s;
    int t = threadIdx.x;
    if (t == 0) carry_s = 0;
    __syncthreads();
    for (int base = 0; base < nb; base += 1024) {
        int idx = base + t;
        int v = (idx < nb) ? p[idx] : 0;
        s[t] = v;
        __syncthreads();
        for (int off = 1; off < 1024; off <<= 1) {
            int u = (t >= off) ? s[t - off] : 0;
            __syncthreads();
            s[t] += u;
            __syncthreads();
        }
        int carry = carry_s;
        if (idx < nb) p[idx] = carry + s[t] - v;
        __syncthreads();
        if (t == 0) carry_s += s[1023];
        __syncthreads();
    }
}

// stage 3: add block offsets
__global__ __launch_bounds__(256) void k_scan3(int* __restrict__ excl,
                                               const int* __restrict__ partials, int n)
{
    int i = blockIdx.x * 256 + threadIdx.x;
    if (i < n) excl[i] += partials[blockIdx.x];
}

// scatter packed edges into own 64B-aligned regions; sentinel-fill pad from
// the scatter cursors (no redundant histogram pass). Zero global atomics.
__global__ __launch_bounds__(256) void k_bin(const void* __restrict__ edges,
                                             const int* __restrict__ flag,
                                             const int* __restrict__ base_blk,
                                             int* __restrict__ epk,
                                             long long E, long long chunk, int NB)
{
    __shared__ int base[MAXNB];
    __shared__ int cur[MAXNB];
    int tid = threadIdx.x;
    for (int b = tid; b < NB; b += 256) {
        base[b] = base_blk[(size_t)b * NBLK + blockIdx.x];
        cur[b] = 0;
    }
    __syncthreads();
    int f64 = *flag;
    long long lo = (long long)blockIdx.x * chunk;
    long long hi = lo + chunk; if (hi > E) hi = E;
    long long len = hi - lo; if (len < 0) len = 0;
    if ((E & 1) == 0) {
        long long nv = len & ~1LL;
        for (long long o = (long long)tid * 2; o < nv; o += 512) {
            int s0, s1, d0, d1;
            if (f64) {
                longlong2 qs = *(const longlong2*)((const long long*)edges + lo + o);
                longlong2 qd = *(const longlong2*)((const long long*)edges + E + lo + o);
                s0 = (int)qs.x; s1 = (int)qs.y; d0 = (int)qd.x; d1 = (int)qd.y;
            } else {
                int2 qs = *(const int2*)((const int*)edges + lo + o);
                int2 qd = *(const int2*)((const int*)edges + E + lo + o);
                s0 = qs.x; s1 = qs.y; d0 = qd.x; d1 = qd.y;
            }
            int b0 = d0 >> BSH;
            int p0 = atomicAdd(&cur[b0], 1);
            epk[base[b0] + p0] = ((d0 & (BSZ - 1)) << 18) | s0;
            int b1 = d1 >> BSH;
            int p1 = atomicAdd(&cur[b1], 1);
            epk[base[b1] + p1] = ((d1 & (BSZ - 1)) << 18) | s1;
        }
        if (tid == 0 && (len & 1)) {
            int s = ld_idx(edges, f64, hi - 1);
            int d = ld_idx(edges, f64, E + hi - 1);
            int b = d >> BSH;
            int p = atomicAdd(&cur[b], 1);
            epk[base[b] + p] = ((d & (BSZ - 1)) << 18) | s;
        }
    } else {
        for (long long i = lo + tid; i < hi; i += 256) {
            int s = ld_idx(edges, f64, i);
            int d = ld_idx(edges, f64, E + i);
            int b = d >> BSH;
            int slot = atomicAdd(&cur[b], 1);
            epk[base[b] + slot] = ((d & (BSZ - 1)) << 18) | s;
        }
    }
    __syncthreads();
    for (int b = tid; b < NB; b += 256) {
        int c = cur[b];
        int r = (c + 15) & ~15;
        for (int j = c; j < r; ++j) epk[base[b] + j] = -1;
    }
}

// within-bucket counting sort -> exact CSR (entries are BYTE offsets src*64);
// fused deg/dinv/row_off.
__global__ __launch_bounds__(256) void k_csr(const int* __restrict__ epk,
                                             const int* __restrict__ base_blk,
                                             int* __restrict__ csr,
                                             int* __restrict__ row_off,
                                             int* __restrict__ degi,
                                             float* __restrict__ dinv, int n)
{
    __shared__ int cnt[BSZ];
    __shared__ int off[BSZ];
    __shared__ int ps[256];
    int b = blockIdx.x;
    int tid = threadIdx.x;
    int start = base_blk[(size_t)b * NBLK];
    int end   = base_blk[(size_t)(b + 1) * NBLK];
    cnt[tid] = 0; cnt[tid + 256] = 0;
    __syncthreads();
    for (int e = start + tid; e < end; e += 256) {
        int pk = __builtin_nontemporal_load(&epk[e]);
        if (pk >= 0) atomicAdd(&cnt[pk >> 18], 1);
    }
    __syncthreads();
    int pairSum = cnt[2 * tid] + cnt[2 * tid + 1];
    ps[tid] = pairSum;
    __syncthreads();
#pragma unroll
    for (int o = 1; o < 256; o <<= 1) {
        int v = (tid >= o) ? ps[tid - o] : 0;
        __syncthreads();
        ps[tid] += v;
        __syncthreads();
    }
    int incl = ps[tid];
    off[2 * tid]     = incl - pairSum;
    off[2 * tid + 1] = incl - pairSum + cnt[2 * tid];
    __syncthreads();
    int nbase = b << BSH;
#pragma unroll
    for (int l = tid; l < BSZ; l += 256) {
        int node = nbase + l;
        if (node < n) {
            row_off[node] = start + off[l];
            degi[node]    = cnt[l];
            dinv[node]    = rsqrtf((float)cnt[l] + 1.0f);
        }
    }
    __syncthreads();
    for (int e = start + tid; e < end; e += 256) {
        int pk = __builtin_nontemporal_load(&epk[e]);
        if (pk < 0) continue;
        int l = pk >> 18;
        int pos = atomicAdd(&off[l], 1);
        csr[start + pos] = (pk & 0x3FFFF) << 6;   // byte offset into hs rows
    }
}

// h = x @ W1 (9->16); hs = h * dinv
__global__ __launch_bounds__(256) void k_lin1(const float* __restrict__ x,
                                              const float* __restrict__ W1,
                                              const float* __restrict__ dinv,
                                              float* __restrict__ hs, int n)
{
    __shared__ float sW[144];
    if (threadIdx.x < 144) sW[threadIdx.x] = W1[threadIdx.x];
    __syncthreads();
    int i = blockIdx.x * 256 + threadIdx.x;
    if (i >= n) return;
    float xv[9];
#pragma unroll
    for (int k = 0; k < 9; ++k) xv[k] = x[(size_t)i * 9 + k];
    float di = dinv[i];
#pragma unroll
    for (int j = 0; j < 16; ++j) {
        float acc = 0.f;
#pragma unroll
        for (int k = 0; k < 9; ++k) acc = fmaf(xv[k], sW[k * 16 + j], acc);
        hs[(size_t)i * 16 + j] = acc * di;
    }
}

// One wave per node, 16 edge-slots x 4 lanes (float4, 2-way unrolled).
// csr entries are byte offsets; csr reads nontemporal (20MB streamed once --
// keep L2 for hs, which has ~20x reuse).
// MODE 0: out = agg = dinv*(hs_self + sum hs[src])
// MODE 1: fused lin: out = (relu(agg + bias) @ W16x16) * dinv
template<int MODE>
__global__ __launch_bounds__(256) void k_gatherF(const int* __restrict__ csr,
                                                 const int* __restrict__ row_off,
                                                 const int* __restrict__ degi,
                                                 const float* __restrict__ dinv,
                                                 const float* __restrict__ hs,
                                                 const float* __restrict__ W,
                                                 const float* __restrict__ bias,
                                                 float* __restrict__ outb, int n)
{
    int wid = (int)(((long long)blockIdx.x * 256 + threadIdx.x) >> 6);
    if (wid >= n) return;
    int lane = threadIdx.x & 63;
    int slot = lane >> 2;          // 16 slots
    int q    = lane & 3;           // float4 quarter of the 16-feature row
    int qb   = q * 16;             // byte offset of the quarter
    int start = row_off[wid];
    int deg   = degi[wid];
    float di  = dinv[wid];
    const char* hp = (const char*)hs;
    float4 sum;
    if (slot == 0) sum = *(const float4*)(hp + (size_t)wid * 64 + qb); // self loop
    else           sum = make_float4(0.f, 0.f, 0.f, 0.f);
    int e = slot;
    for (; e + 16 < deg; e += 32) {                    // 2 lines in flight/lane
        int o0 = __builtin_nontemporal_load(&csr[start + e]);
        int o1 = __builtin_nontemporal_load(&csr[start + e + 16]);
        float4 v0 = *(const float4*)(hp + (size_t)(unsigned)o0 + qb);
        float4 v1 = *(const float4*)(hp + (size_t)(unsigned)o1 + qb);
        sum.x += v0.x + v1.x; sum.y += v0.y + v1.y;
        sum.z += v0.z + v1.z; sum.w += v0.w + v1.w;
    }
    if (e < deg) {
        int o0 = __builtin_nontemporal_load(&csr[start + e]);
        float4 v0 = *(const float4*)(hp + (size_t)(unsigned)o0 + qb);
        sum.x += v0.x; sum.y += v0.y; sum.z += v0.z; sum.w += v0.w;
    }
#pragma unroll
    for (int off = 4; off < 64; off <<= 1) {
        sum.x += __shfl_xor(sum.x, off);
        sum.y += __shfl_xor(sum.y, off);
        sum.z += __shfl_xor(sum.z, off);
        sum.w += __shfl_xor(sum.w, off);
    }
    float4 aq = make_float4(sum.x * di, sum.y * di, sum.z * di, sum.w * di);

    if (MODE == 0) {
        if (slot == 0) *(float4*)&outb[(size_t)wid * 16 + q * 4] = aq;
    } else {
        float t[16];
#pragma unroll
        for (int a = 0; a < 4; ++a) {
            t[4 * a + 0] = __shfl(aq.x, a);
            t[4 * a + 1] = __shfl(aq.y, a);
            t[4 * a + 2] = __shfl(aq.z, a);
            t[4 * a + 3] = __shfl(aq.w, a);
        }
#pragma unroll
        for (int k = 0; k < 16; ++k) {
            float v = t[k] + bias[k];
            t[k] = v > 0.f ? v : 0.f;
        }
        int j = lane & 15;
        float o = 0.f;
#pragma unroll
        for (int k = 0; k < 16; ++k)
            o = fmaf(t[k], W[k * 16 + j], o);
        if (lane < 16) outb[(size_t)wid * 16 + j] = o * di;
    }
}

// convert + transpose MLP weights to bf16: Wl2T[128 col][32 k] (k>=25 zero),
// Wl3T[128 col][128 k]
__global__ __launch_bounds__(256) void k_cvt(const float* __restrict__ Wl2,
                                             const float* __restrict__ Wl3,
                                             unsigned short* __restrict__ Wl2T,
                                             unsigned short* __restrict__ Wl3T)
{
    int i = blockIdx.x * 256 + threadIdx.x;
    if (i < 128 * 32) {
        int c = i >> 5, k = i & 31;
        float v = (k < 25) ? Wl2[k * 128 + c] : 0.f;
        Wl2T[i] = f2b(v);
    }
    int j = i - 128 * 32;
    if (j >= 0 && j < 128 * 128) {
        int c = j >> 7, k = j & 127;
        Wl3T[j] = f2b(Wl3[k * 128 + c]);
    }
}

// MLP head on matrix cores (bf16 in, fp32 accumulate):
// feat=[x(9),relu(agg3+b3)(16)] pad32 bf16; z=relu(feat@Wl2+bl2) bf16 in LDS
// (XOR swizzle byte^=(row&7)<<4 on 256B rows -> conflict-free A-frag reads);
// z2=relu(z@Wl3+bl3); out=z2@Wl4+bl4 (f32 epilogue).
// 4 waves/block, 16 nodes/wave. mfma_f32_16x16x32_bf16:
//   A: [m=lane&15][k=8*(lane>>4)+j]; B: [k=8*(lane>>4)+j][n=lane&15];
//   D: [m=(lane>>4)*4+r][n=lane&15]   (C/D verified layout, m89)
__global__ __launch_bounds__(256) void k_mlp(const float* __restrict__ x,
                                             const float* __restrict__ agg3,
                                             const float* __restrict__ b3,
                                             const unsigned short* __restrict__ Wl2T,
                                             const float* __restrict__ bl2,
                                             const unsigned short* __restrict__ Wl3T,
                                             const float* __restrict__ bl3,
                                             const float* __restrict__ Wl4,
                                             const float* __restrict__ bl4,
                                             float* __restrict__ out, int n)
{
    __shared__ __align__(16) unsigned short featb[4][16 * 40];  // stride 40 (80B)
    __shared__ __align__(16) unsigned short zb[4][16 * 128];    // 256B rows, swizzled

    int tid  = threadIdx.x;
    int w    = tid >> 6;
    int lane = tid & 63;
    int g    = lane >> 4;      // 0..3
    int l15  = lane & 15;
    int base = (blockIdx.x * 4 + w) * 16;

    // stage feat bf16 [16][32] (cols 25..31 zero)
    for (int idx = lane; idx < 16 * 32; idx += 64) {
        int nn = idx >> 5, f = idx & 31;
        int node = base + nn;
        float v = 0.f;
        if (node < n) {
            if (f < 9) v = x[(size_t)node * 9 + f];
            else if (f < 25) {
                float t = agg3[(size_t)node * 16 + (f - 9)] + b3[f - 9];
                v = t > 0.f ? t : 0.f;
            }
        }
        featb[w][nn * 40 + f] = f2b(v);
    }
    __syncthreads();

    // ---- layer l2: z[16][128] = relu(feat @ Wl2 + bl2), one K=32 MFMA/tile ----
    bf16x8 a2 = *(const bf16x8*)&featb[w][l15 * 40 + 8 * g];
    char* zbw = (char*)&zb[w][0];
#pragma unroll
    for (int t = 0; t < 8; ++t) {
        int col = l15 + 16 * t;
        bf16x8 b2 = *(const bf16x8*)&Wl2T[(size_t)col * 32 + 8 * g];
        f32x4 c = {0.f, 0.f, 0.f, 0.f};
        c = __builtin_amdgcn_mfma_f32_16x16x32_bf16(a2, b2, c, 0, 0, 0);
        float bb = bl2[col];
#pragma unroll
        for (int r = 0; r < 4; ++r) {
            int node = g * 4 + r;
            float v = c[r] + bb;
            v = v > 0.f ? v : 0.f;
            int byte = node * 256 + ((2 * col) ^ ((node & 7) << 4));
            *(unsigned short*)(zbw + byte) = f2b(v);
        }
    }
    __syncthreads();

    // ---- layer l3: z[16][128] @ Wl3[128][128], 4 K-steps x 8 N-tiles ----
    f32x4 acc[8];
#pragma unroll
    for (int t = 0; t < 8; ++t) acc[t] = (f32x4){0.f, 0.f, 0.f, 0.f};
#pragma unroll
    for (int s = 0; s < 4; ++s) {
        int kb = 8 * g + 32 * s;
        int byteA = l15 * 256 + ((2 * kb) ^ ((l15 & 7) << 4));
        bf16x8 a3 = *(const bf16x8*)(zbw + byteA);
#pragma unroll
        for (int t = 0; t < 8; ++t) {
            bf16x8 b3f = *(const bf16x8*)&Wl3T[(size_t)(l15 + 16 * t) * 128 + kb];
            acc[t] = __builtin_amdgcn_mfma_f32_16x16x32_bf16(a3, b3f, acc[t], 0, 0, 0);
        }
    }

    // ---- layer l4: relu, dot with Wl4, reduce over the 16 n-lanes ----
    float p[4] = {0.f, 0.f, 0.f, 0.f};
#pragma unroll
    for (int t = 0; t < 8; ++t) {
        int col = l15 + 16 * t;
        float b3v = bl3[col];
        float w4  = Wl4[col];
#pragma unroll
        for (int r = 0; r < 4; ++r) {
            float v = acc[t][r] + b3v;
            v = v > 0.f ? v : 0.f;
            p[r] = fmaf(v, w4, p[r]);
        }
    }
    float bb = bl4[0];
#pragma unroll
    for (int r = 0; r < 4; ++r) {
        float s = p[r];
        s += __shfl_xor(s, 1);
        s += __shfl_xor(s, 2);
        s += __shfl_xor(s, 4);
        s += __shfl_xor(s, 8);
        int node = base + g * 4 + r;
        if (l15 == 0 && node < n) out[node] = s + bb;
    }
}

extern "C" void kernel_launch(void* const* d_in, const int* in_sizes, int n_in,
                              void* d_out, int out_size, void* d_ws, size_t ws_size,
                              hipStream_t stream)
{
    const float* x   = (const float*)d_in[0];
    const void*  ei  = d_in[1];
    const float* W1  = (const float*)d_in[2];
    const float* b1  = (const float*)d_in[3];
    const float* W2  = (const float*)d_in[4];
    const float* b2  = (const float*)d_in[5];
    const float* W3  = (const float*)d_in[6];
    const float* b3  = (const float*)d_in[7];
    const float* Wl2 = (const float*)d_in[8];
    const float* bl2 = (const float*)d_in[9];
    const float* Wl3 = (const float*)d_in[10];
    const float* bl3 = (const float*)d_in[11];
    const float* Wl4 = (const float*)d_in[12];
    const float* bl4 = (const float*)d_in[13];
    float* out = (float*)d_out;

    int n        = in_sizes[0] / 9;          // 250000
    long long e2 = (long long)in_sizes[1];   // 2*E
    long long E  = e2 / 2;
    int NB       = (n + BSZ - 1) >> BSH;     // 489 buckets
    int L        = NB * NBLK + 1;            // scan length (extra slot = total)
    long long chunk = (((E + NBLK - 1) / NBLK) + 1) & ~1LL;   // even chunk
    size_t EPAD  = (size_t)E + (size_t)NBLK * NB * 16;   // binned region elems

    char* ws = (char*)d_ws;
    size_t off = 0;
    int*   flag     = (int*)(ws + off); off += 256;
    int*   cnt_blk  = (int*)(ws + off); off += (size_t)L * 4;        off = (off + 255) & ~(size_t)255;
    int*   base_blk = (int*)(ws + off); off += (size_t)L * 4;        off = (off + 255) & ~(size_t)255;
    int*   partials = (int*)(ws + off); off += 16384;
    unsigned short* wl2t = (unsigned short*)(ws + off); off += 128 * 32 * 2;
    off = (off + 255) & ~(size_t)255;
    unsigned short* wl3t = (unsigned short*)(ws + off); off += 128 * 128 * 2;
    off = (off + 255) & ~(size_t)255;
    float* dinv     = (float*)(ws + off); off += (size_t)n * 4;      off = (off + 255) & ~(size_t)255;
    int*   degi     = (int*)(ws + off); off += (size_t)n * 4;        off = (off + 255) & ~(size_t)255;
    int*   row_off  = (int*)(ws + off); off += (size_t)n * 4;        off = (off + 255) & ~(size_t)255;
    int*   csr      = (int*)(ws + off); off += EPAD * 4;             off = (off + 255) & ~(size_t)255;
    int*   epk      = (int*)(ws + off); off += EPAD * 4;             off = (off + 255) & ~(size_t)255;
    // bufA/bufB alias epk (dead after k_csr); EPAD*4 = 36 MB >= 32 MB needed
    float* bufA = (float*)epk;
    float* bufB = bufA + (size_t)n * 16;

    int nb_n = (n + 255) / 256;
    int nb_s = (L + 255) / 256;

    k_detect<<<1, 64, 0, stream>>>(ei, flag, n);
    hipMemsetAsync(cnt_blk + (L - 1), 0, 4, stream);   // extra slot -> total
    k_cvt<<<80, 256, 0, stream>>>(Wl2, Wl3, wl2t, wl3t);
    k_hist2<<<NBLK, 256, 0, stream>>>(ei, flag, cnt_blk, E, chunk, NB);
    k_scan1<<<nb_s, 256, 0, stream>>>(cnt_blk, base_blk, partials, L);
    k_scan2<<<1, 1024, 0, stream>>>(partials, nb_s);
    k_scan3<<<nb_s, 256, 0, stream>>>(base_blk, partials, L);
    k_bin<<<NBLK, 256, 0, stream>>>(ei, flag, base_blk, epk, E, chunk, NB);
    k_csr<<<NB, 256, 0, stream>>>(epk, base_blk, csr, row_off, degi, dinv, n);

    int nb_g = (n + 3) / 4;   // one wave per node, 4 waves/block
    // layer 1 transform
    k_lin1<<<nb_n, 256, 0, stream>>>(x, W1, dinv, bufA, n);
    // gather1 + fused lin2:  bufA -> bufB
    k_gatherF<1><<<nb_g, 256, 0, stream>>>(csr, row_off, degi, dinv, bufA, W2, b1,
                                           bufB, n);
    // gather2 + fused lin3:  bufB -> bufA
    k_gatherF<1><<<nb_g, 256, 0, stream>>>(csr, row_off, degi, dinv, bufB, W3, b2,
                                           bufA, n);
    // gather3 (plain agg):   bufA -> bufB
    k_gatherF<0><<<nb_g, 256, 0, stream>>>(csr, row_off, degi, dinv, bufA, nullptr,
                                           nullptr, bufB, n);
    // MLP head (bf16 MFMA)
    k_mlp<<<(n + 63) / 64, 256, 0, stream>>>(x, bufB, b3, wl2t, bl2, wl3t, bl3,
                                             Wl4, bl4, out, n);
}

// Round 14
// 513.178 us; speedup vs baseline: 1.1135x; 1.1135x over previous
//
#include <hip/hip_runtime.h>

// ---------------------------------------------------------------------------
// GCN: 3x GCNConv(9->16->16->16) + MLP(concat 25 ->128->128->1), N=250000,
// E=5,000,000 edges + self loops. f32 in/out; edge_index int32 OR int64
// (detected on device).
// Pipeline: deterministic 2-pass binning into 512-node buckets (single-writer
// 64B lines, zero global atomics; k_bin sentinel-fills from its scatter
// cursors -- no redundant histogram pass) -> within-bucket counting sort to
// exact CSR (fused deg/dinv) -> per-node wave gather (f32 rows, 16 slots x
// float4; bf16 rows REGRESSED r11: random access is billed in 64B lines and
// unpack doubles VALU; nontemporal csr loads REGRESSED r13: csr is a
// read-broadcast stream that L1 handles -- bypassing it adds misses) with
// fused 16x16 linear epilogue -> bf16 MFMA MLP head (16x16x32, fp32 acc).
// NOTE: k_mlp uses plain __launch_bounds__(256): any min-waves second arg
// makes the allocator cap at 64 VGPRs and spill the acc tile to scratch
// (observed r2/r5/r6: 190MB scratch traffic, 2-3x slowdown).
// ---------------------------------------------------------------------------

#define NBLK 512          // binning blocks (each owns a contiguous edge chunk)
#define BSH  9            // bucket shift: 512 nodes per bucket
#define BSZ  512
#define MAXNB 1024        // max buckets supported (n <= 524288)

typedef __attribute__((ext_vector_type(8))) __bf16 bf16x8;
typedef __attribute__((ext_vector_type(4))) float  f32x4;

__device__ __forceinline__ unsigned short f2b(float f)   // f32 -> bf16 RNE
{
    unsigned u = __float_as_uint(f);
    unsigned r = (u + 0x7FFFu + ((u >> 16) & 1u)) >> 16;
    return (unsigned short)r;
}

__global__ __launch_bounds__(64) void k_detect(const void* __restrict__ edges,
                                               int* __restrict__ flag, int n_nodes)
{
    if (threadIdx.x == 0 && blockIdx.x == 0) {
        const long long* p = (const long long*)edges;
        int is64 = 1;
        for (int i = 0; i < 16; ++i) {
            long long v = p[i];
            if (v < 0 || v >= (long long)n_nodes) is64 = 0;
        }
        *flag = is64;
    }
}

// little-endian: low 32 bits of int64 value < 2^31 equal the int32 value
__device__ __forceinline__ int ld_idx(const void* edges, int f64, long long idx)
{
    return f64 ? ((const int*)edges)[idx << 1] : ((const int*)edges)[idx];
}

// per-block bucket histogram of dst; write rounded-to-16 counts bucket-major.
// 2-wide vectorized reads (chunk forced even; alignment-guarded).
__global__ __launch_bounds__(256) void k_hist2(const void* __restrict__ edges,
                                               const int* __restrict__ flag,
                                               int* __restrict__ cnt_blk,
                                               long long E, long long chunk, int NB)
{
    __shared__ int cnt[MAXNB];
    int tid = threadIdx.x;
    for (int b = tid; b < NB; b += 256) cnt[b] = 0;
    __syncthreads();
    int f64 = *flag;
    long long lo = (long long)blockIdx.x * chunk;
    long long hi = lo + chunk; if (hi > E) hi = E;
    long long len = hi - lo; if (len < 0) len = 0;
    if ((E & 1) == 0) {                       // vector path (lo even by chunk)
        long long nv = len & ~1LL;
        for (long long o = (long long)tid * 2; o < nv; o += 512) {
            int d0, d1;
            if (f64) {
                longlong2 q = *(const longlong2*)((const long long*)edges + E + lo + o);
                d0 = (int)q.x; d1 = (int)q.y;
            } else {
                int2 q = *(const int2*)((const int*)edges + E + lo + o);
                d0 = q.x; d1 = q.y;
            }
            atomicAdd(&cnt[d0 >> BSH], 1);
            atomicAdd(&cnt[d1 >> BSH], 1);
        }
        if (tid == 0 && (len & 1)) {
            int d = ld_idx(edges, f64, E + hi - 1);
            atomicAdd(&cnt[d >> BSH], 1);
        }
    } else {
        for (long long i = lo + tid; i < hi; i += 256) {
            int d = ld_idx(edges, f64, E + i);
            atomicAdd(&cnt[d >> BSH], 1);
        }
    }
    __syncthreads();
    for (int b = tid; b < NB; b += 256)
        cnt_blk[(size_t)b * NBLK + blockIdx.x] = (cnt[b] + 15) & ~15;
}

// exclusive scan stage 1
__global__ __launch_bounds__(256) void k_scan1(const int* __restrict__ in,
                                               int* __restrict__ excl,
                                               int* __restrict__ partials, int n)
{
    __shared__ int s[256];
    int tid = threadIdx.x;
    int i = blockIdx.x * 256 + tid;
    int v = (i < n) ? in[i] : 0;
    s[tid] = v;
    __syncthreads();
#pragma unroll
    for (int off = 1; off < 256; off <<= 1) {
        int t = (tid >= off) ? s[tid - off] : 0;
        __syncthreads();
        s[tid] += t;
        __syncthreads();
    }
    if (i < n) excl[i] = s[tid] - v;
    if (tid == 255) partials[blockIdx.x] = s[255];
}

// stage 2: single block, exclusive scan of partials (carry loop)
__global__ __launch_bounds__(1024) void k_scan2(int* __restrict__ p, int nb)
{
    __shared__ int s[1024];
    __shared__ int carry_s;
    int t = threadIdx.x;
    if (t == 0) carry_s = 0;
    __syncthreads();
    for (int base = 0; base < nb; base += 1024) {
        int idx = base + t;
        int v = (idx < nb) ? p[idx] : 0;
        s[t] = v;
        __syncthreads();
        for (int off = 1; off < 1024; off <<= 1) {
            int u = (t >= off) ? s[t - off] : 0;
            __syncthreads();
            s[t] += u;
            __syncthreads();
        }
        int carry = carry_s;
        if (idx < nb) p[idx] = carry + s[t] - v;
        __syncthreads();
        if (t == 0) carry_s += s[1023];
        __syncthreads();
    }
}

// stage 3: add block offsets
__global__ __launch_bounds__(256) void k_scan3(int* __restrict__ excl,
                                               const int* __restrict__ partials, int n)
{
    int i = blockIdx.x * 256 + threadIdx.x;
    if (i < n) excl[i] += partials[blockIdx.x];
}

// scatter packed edges into own 64B-aligned regions; sentinel-fill pad from
// the scatter cursors (no redundant histogram pass). Zero global atomics.
__global__ __launch_bounds__(256) void k_bin(const void* __restrict__ edges,
                                             const int* __restrict__ flag,
                                             const int* __restrict__ base_blk,
                                             int* __restrict__ epk,
                                             long long E, long long chunk, int NB)
{
    __shared__ int base[MAXNB];
    __shared__ int cur[MAXNB];
    int tid = threadIdx.x;
    for (int b = tid; b < NB; b += 256) {
        base[b] = base_blk[(size_t)b * NBLK + blockIdx.x];
        cur[b] = 0;
    }
    __syncthreads();
    int f64 = *flag;
    long long lo = (long long)blockIdx.x * chunk;
    long long hi = lo + chunk; if (hi > E) hi = E;
    long long len = hi - lo; if (len < 0) len = 0;
    if ((E & 1) == 0) {
        long long nv = len & ~1LL;
        for (long long o = (long long)tid * 2; o < nv; o += 512) {
            int s0, s1, d0, d1;
            if (f64) {
                longlong2 qs = *(const longlong2*)((const long long*)edges + lo + o);
                longlong2 qd = *(const longlong2*)((const long long*)edges + E + lo + o);
                s0 = (int)qs.x; s1 = (int)qs.y; d0 = (int)qd.x; d1 = (int)qd.y;
            } else {
                int2 qs = *(const int2*)((const int*)edges + lo + o);
                int2 qd = *(const int2*)((const int*)edges + E + lo + o);
                s0 = qs.x; s1 = qs.y; d0 = qd.x; d1 = qd.y;
            }
            int b0 = d0 >> BSH;
            int p0 = atomicAdd(&cur[b0], 1);
            epk[base[b0] + p0] = ((d0 & (BSZ - 1)) << 18) | s0;
            int b1 = d1 >> BSH;
            int p1 = atomicAdd(&cur[b1], 1);
            epk[base[b1] + p1] = ((d1 & (BSZ - 1)) << 18) | s1;
        }
        if (tid == 0 && (len & 1)) {
            int s = ld_idx(edges, f64, hi - 1);
            int d = ld_idx(edges, f64, E + hi - 1);
            int b = d >> BSH;
            int p = atomicAdd(&cur[b], 1);
            epk[base[b] + p] = ((d & (BSZ - 1)) << 18) | s;
        }
    } else {
        for (long long i = lo + tid; i < hi; i += 256) {
            int s = ld_idx(edges, f64, i);
            int d = ld_idx(edges, f64, E + i);
            int b = d >> BSH;
            int slot = atomicAdd(&cur[b], 1);
            epk[base[b] + slot] = ((d & (BSZ - 1)) << 18) | s;
        }
    }
    __syncthreads();
    for (int b = tid; b < NB; b += 256) {
        int c = cur[b];
        int r = (c + 15) & ~15;
        for (int j = c; j < r; ++j) epk[base[b] + j] = -1;
    }
}

// within-bucket counting sort -> exact CSR; fused deg/dinv/row_off.
__global__ __launch_bounds__(256) void k_csr(const int* __restrict__ epk,
                                             const int* __restrict__ base_blk,
                                             int* __restrict__ csr,
                                             int* __restrict__ row_off,
                                             int* __restrict__ degi,
                                             float* __restrict__ dinv, int n)
{
    __shared__ int cnt[BSZ];
    __shared__ int off[BSZ];
    __shared__ int ps[256];
    int b = blockIdx.x;
    int tid = threadIdx.x;
    int start = base_blk[(size_t)b * NBLK];
    int end   = base_blk[(size_t)(b + 1) * NBLK];
    cnt[tid] = 0; cnt[tid + 256] = 0;
    __syncthreads();
    for (int e = start + tid; e < end; e += 256) {
        int pk = epk[e];
        if (pk >= 0) atomicAdd(&cnt[pk >> 18], 1);
    }
    __syncthreads();
    int pairSum = cnt[2 * tid] + cnt[2 * tid + 1];
    ps[tid] = pairSum;
    __syncthreads();
#pragma unroll
    for (int o = 1; o < 256; o <<= 1) {
        int v = (tid >= o) ? ps[tid - o] : 0;
        __syncthreads();
        ps[tid] += v;
        __syncthreads();
    }
    int incl = ps[tid];
    off[2 * tid]     = incl - pairSum;
    off[2 * tid + 1] = incl - pairSum + cnt[2 * tid];
    __syncthreads();
    int nbase = b << BSH;
#pragma unroll
    for (int l = tid; l < BSZ; l += 256) {
        int node = nbase + l;
        if (node < n) {
            row_off[node] = start + off[l];
            degi[node]    = cnt[l];
            dinv[node]    = rsqrtf((float)cnt[l] + 1.0f);
        }
    }
    __syncthreads();
    for (int e = start + tid; e < end; e += 256) {
        int pk = epk[e];
        if (pk < 0) continue;
        int l = pk >> 18;
        int pos = atomicAdd(&off[l], 1);
        csr[start + pos] = pk & 0x3FFFF;
    }
}

// h = x @ W1 (9->16); hs = h * dinv
__global__ __launch_bounds__(256) void k_lin1(const float* __restrict__ x,
                                              const float* __restrict__ W1,
                                              const float* __restrict__ dinv,
                                              float* __restrict__ hs, int n)
{
    __shared__ float sW[144];
    if (threadIdx.x < 144) sW[threadIdx.x] = W1[threadIdx.x];
    __syncthreads();
    int i = blockIdx.x * 256 + threadIdx.x;
    if (i >= n) return;
    float xv[9];
#pragma unroll
    for (int k = 0; k < 9; ++k) xv[k] = x[(size_t)i * 9 + k];
    float di = dinv[i];
#pragma unroll
    for (int j = 0; j < 16; ++j) {
        float acc = 0.f;
#pragma unroll
        for (int k = 0; k < 9; ++k) acc = fmaf(xv[k], sW[k * 16 + j], acc);
        hs[(size_t)i * 16 + j] = acc * di;
    }
}

// One wave per node, 16 edge-slots x 4 lanes (float4, 2-way unrolled).
// MODE 0: out = agg = dinv*(hs_self + sum hs[src])
// MODE 1: fused lin: out = (relu(agg + bias) @ W16x16) * dinv
template<int MODE>
__global__ __launch_bounds__(256) void k_gatherF(const int* __restrict__ csr,
                                                 const int* __restrict__ row_off,
                                                 const int* __restrict__ degi,
                                                 const float* __restrict__ dinv,
                                                 const float* __restrict__ hs,
                                                 const float* __restrict__ W,
                                                 const float* __restrict__ bias,
                                                 float* __restrict__ outb, int n)
{
    int wid = (int)(((long long)blockIdx.x * 256 + threadIdx.x) >> 6);
    if (wid >= n) return;
    int lane = threadIdx.x & 63;
    int slot = lane >> 2;          // 16 slots
    int q    = lane & 3;           // float4 quarter of the 16-feature row
    int start = row_off[wid];
    int deg   = degi[wid];
    float di  = dinv[wid];
    float4 sum;
    if (slot == 0) sum = *(const float4*)&hs[(size_t)wid * 16 + q * 4]; // self loop
    else           sum = make_float4(0.f, 0.f, 0.f, 0.f);
    int e = slot;
    for (; e + 16 < deg; e += 32) {                    // 2 lines in flight/lane
        int s0 = csr[start + e];
        int s1 = csr[start + e + 16];
        float4 v0 = *(const float4*)&hs[(size_t)s0 * 16 + q * 4];
        float4 v1 = *(const float4*)&hs[(size_t)s1 * 16 + q * 4];
        sum.x += v0.x + v1.x; sum.y += v0.y + v1.y;
        sum.z += v0.z + v1.z; sum.w += v0.w + v1.w;
    }
    if (e < deg) {
        int s0 = csr[start + e];
        float4 v0 = *(const float4*)&hs[(size_t)s0 * 16 + q * 4];
        sum.x += v0.x; sum.y += v0.y; sum.z += v0.z; sum.w += v0.w;
    }
#pragma unroll
    for (int off = 4; off < 64; off <<= 1) {
        sum.x += __shfl_xor(sum.x, off);
        sum.y += __shfl_xor(sum.y, off);
        sum.z += __shfl_xor(sum.z, off);
        sum.w += __shfl_xor(sum.w, off);
    }
    float4 aq = make_float4(sum.x * di, sum.y * di, sum.z * di, sum.w * di);

    if (MODE == 0) {
        if (slot == 0) *(float4*)&outb[(size_t)wid * 16 + q * 4] = aq;
    } else {
        float t[16];
#pragma unroll
        for (int a = 0; a < 4; ++a) {
            t[4 * a + 0] = __shfl(aq.x, a);
            t[4 * a + 1] = __shfl(aq.y, a);
            t[4 * a + 2] = __shfl(aq.z, a);
            t[4 * a + 3] = __shfl(aq.w, a);
        }
#pragma unroll
        for (int k = 0; k < 16; ++k) {
            float v = t[k] + bias[k];
            t[k] = v > 0.f ? v : 0.f;
        }
        int j = lane & 15;
        float o = 0.f;
#pragma unroll
        for (int k = 0; k < 16; ++k)
            o = fmaf(t[k], W[k * 16 + j], o);
        if (lane < 16) outb[(size_t)wid * 16 + j] = o * di;
    }
}

// convert + transpose MLP weights to bf16: Wl2T[128 col][32 k] (k>=25 zero),
// Wl3T[128 col][128 k]
__global__ __launch_bounds__(256) void k_cvt(const float* __restrict__ Wl2,
                                             const float* __restrict__ Wl3,
                                             unsigned short* __restrict__ Wl2T,
                                             unsigned short* __restrict__ Wl3T)
{
    int i = blockIdx.x * 256 + threadIdx.x;
    if (i < 128 * 32) {
        int c = i >> 5, k = i & 31;
        float v = (k < 25) ? Wl2[k * 128 + c] : 0.f;
        Wl2T[i] = f2b(v);
    }
    int j = i - 128 * 32;
    if (j >= 0 && j < 128 * 128) {
        int c = j >> 7, k = j & 127;
        Wl3T[j] = f2b(Wl3[k * 128 + c]);
    }
}

// MLP head on matrix cores (bf16 in, fp32 accumulate):
// feat=[x(9),relu(agg3+b3)(16)] pad32 bf16; z=relu(feat@Wl2+bl2) bf16 in LDS
// (XOR swizzle byte^=(row&7)<<4 on 256B rows -> conflict-free A-frag reads);
// z2=relu(z@Wl3+bl3); out=z2@Wl4+bl4 (f32 epilogue).
// 4 waves/block, 16 nodes/wave. mfma_f32_16x16x32_bf16:
//   A: [m=lane&15][k=8*(lane>>4)+j]; B: [k=8*(lane>>4)+j][n=lane&15];
//   D: [m=(lane>>4)*4+r][n=lane&15]   (C/D verified layout, m89)
__global__ __launch_bounds__(256) void k_mlp(const float* __restrict__ x,
                                             const float* __restrict__ agg3,
                                             const float* __restrict__ b3,
                                             const unsigned short* __restrict__ Wl2T,
                                             const float* __restrict__ bl2,
                                             const unsigned short* __restrict__ Wl3T,
                                             const float* __restrict__ bl3,
                                             const float* __restrict__ Wl4,
                                             const float* __restrict__ bl4,
                                             float* __restrict__ out, int n)
{
    __shared__ __align__(16) unsigned short featb[4][16 * 40];  // stride 40 (80B)
    __shared__ __align__(16) unsigned short zb[4][16 * 128];    // 256B rows, swizzled

    int tid  = threadIdx.x;
    int w    = tid >> 6;
    int lane = tid & 63;
    int g    = lane >> 4;      // 0..3
    int l15  = lane & 15;
    int base = (blockIdx.x * 4 + w) * 16;

    // stage feat bf16 [16][32] (cols 25..31 zero)
    for (int idx = lane; idx < 16 * 32; idx += 64) {
        int nn = idx >> 5, f = idx & 31;
        int node = base + nn;
        float v = 0.f;
        if (node < n) {
            if (f < 9) v = x[(size_t)node * 9 + f];
            else if (f < 25) {
                float t = agg3[(size_t)node * 16 + (f - 9)] + b3[f - 9];
                v = t > 0.f ? t : 0.f;
            }
        }
        featb[w][nn * 40 + f] = f2b(v);
    }
    __syncthreads();

    // ---- layer l2: z[16][128] = relu(feat @ Wl2 + bl2), one K=32 MFMA/tile ----
    bf16x8 a2 = *(const bf16x8*)&featb[w][l15 * 40 + 8 * g];
    char* zbw = (char*)&zb[w][0];
#pragma unroll
    for (int t = 0; t < 8; ++t) {
        int col = l15 + 16 * t;
        bf16x8 b2 = *(const bf16x8*)&Wl2T[(size_t)col * 32 + 8 * g];
        f32x4 c = {0.f, 0.f, 0.f, 0.f};
        c = __builtin_amdgcn_mfma_f32_16x16x32_bf16(a2, b2, c, 0, 0, 0);
        float bb = bl2[col];
#pragma unroll
        for (int r = 0; r < 4; ++r) {
            int node = g * 4 + r;
            float v = c[r] + bb;
            v = v > 0.f ? v : 0.f;
            int byte = node * 256 + ((2 * col) ^ ((node & 7) << 4));
            *(unsigned short*)(zbw + byte) = f2b(v);
        }
    }
    __syncthreads();

    // ---- layer l3: z[16][128] @ Wl3[128][128], 4 K-steps x 8 N-tiles ----
    f32x4 acc[8];
#pragma unroll
    for (int t = 0; t < 8; ++t) acc[t] = (f32x4){0.f, 0.f, 0.f, 0.f};
#pragma unroll
    for (int s = 0; s < 4; ++s) {
        int kb = 8 * g + 32 * s;
        int byteA = l15 * 256 + ((2 * kb) ^ ((l15 & 7) << 4));
        bf16x8 a3 = *(const bf16x8*)(zbw + byteA);
#pragma unroll
        for (int t = 0; t < 8; ++t) {
            bf16x8 b3f = *(const bf16x8*)&Wl3T[(size_t)(l15 + 16 * t) * 128 + kb];
            acc[t] = __builtin_amdgcn_mfma_f32_16x16x32_bf16(a3, b3f, acc[t], 0, 0, 0);
        }
    }

    // ---- layer l4: relu, dot with Wl4, reduce over the 16 n-lanes ----
    float p[4] = {0.f, 0.f, 0.f, 0.f};
#pragma unroll
    for (int t = 0; t < 8; ++t) {
        int col = l15 + 16 * t;
        float b3v = bl3[col];
        float w4  = Wl4[col];
#pragma unroll
        for (int r = 0; r < 4; ++r) {
            float v = acc[t][r] + b3v;
            v = v > 0.f ? v : 0.f;
            p[r] = fmaf(v, w4, p[r]);
        }
    }
    float bb = bl4[0];
#pragma unroll
    for (int r = 0; r < 4; ++r) {
        float s = p[r];
        s += __shfl_xor(s, 1);
        s += __shfl_xor(s, 2);
        s += __shfl_xor(s, 4);
        s += __shfl_xor(s, 8);
        int node = base + g * 4 + r;
        if (l15 == 0 && node < n) out[node] = s + bb;
    }
}

extern "C" void kernel_launch(void* const* d_in, const int* in_sizes, int n_in,
                              void* d_out, int out_size, void* d_ws, size_t ws_size,
                              hipStream_t stream)
{
    const float* x   = (const float*)d_in[0];
    const void*  ei  = d_in[1];
    const float* W1  = (const float*)d_in[2];
    const float* b1  = (const float*)d_in[3];
    const float* W2  = (const float*)d_in[4];
    const float* b2  = (const float*)d_in[5];
    const float* W3  = (const float*)d_in[6];
    const float* b3  = (const float*)d_in[7];
    const float* Wl2 = (const float*)d_in[8];
    const float* bl2 = (const float*)d_in[9];
    const float* Wl3 = (const float*)d_in[10];
    const float* bl3 = (const float*)d_in[11];
    const float* Wl4 = (const float*)d_in[12];
    const float* bl4 = (const float*)d_in[13];
    float* out = (float*)d_out;

    int n        = in_sizes[0] / 9;          // 250000
    long long e2 = (long long)in_sizes[1];   // 2*E
    long long E  = e2 / 2;
    int NB       = (n + BSZ - 1) >> BSH;     // 489 buckets
    int L        = NB * NBLK + 1;            // scan length (extra slot = total)
    long long chunk = (((E + NBLK - 1) / NBLK) + 1) & ~1LL;   // even chunk
    size_t EPAD  = (size_t)E + (size_t)NBLK * NB * 16;   // binned region elems

    char* ws = (char*)d_ws;
    size_t off = 0;
    int*   flag     = (int*)(ws + off); off += 256;
    int*   cnt_blk  = (int*)(ws + off); off += (size_t)L * 4;        off = (off + 255) & ~(size_t)255;
    int*   base_blk = (int*)(ws + off); off += (size_t)L * 4;        off = (off + 255) & ~(size_t)255;
    int*   partials = (int*)(ws + off); off += 16384;
    unsigned short* wl2t = (unsigned short*)(ws + off); off += 128 * 32 * 2;
    off = (off + 255) & ~(size_t)255;
    unsigned short* wl3t = (unsigned short*)(ws + off); off += 128 * 128 * 2;
    off = (off + 255) & ~(size_t)255;
    float* dinv     = (float*)(ws + off); off += (size_t)n * 4;      off = (off + 255) & ~(size_t)255;
    int*   degi     = (int*)(ws + off); off += (size_t)n * 4;        off = (off + 255) & ~(size_t)255;
    int*   row_off  = (int*)(ws + off); off += (size_t)n * 4;        off = (off + 255) & ~(size_t)255;
    int*   csr      = (int*)(ws + off); off += EPAD * 4;             off = (off + 255) & ~(size_t)255;
    int*   epk      = (int*)(ws + off); off += EPAD * 4;             off = (off + 255) & ~(size_t)255;
    // bufA/bufB alias epk (dead after k_csr); EPAD*4 = 36 MB >= 32 MB needed
    float* bufA = (float*)epk;
    float* bufB = bufA + (size_t)n * 16;

    int nb_n = (n + 255) / 256;
    int nb_s = (L + 255) / 256;

    k_detect<<<1, 64, 0, stream>>>(ei, flag, n);
    hipMemsetAsync(cnt_blk + (L - 1), 0, 4, stream);   // extra slot -> total
    k_cvt<<<80, 256, 0, stream>>>(Wl2, Wl3, wl2t, wl3t);
    k_hist2<<<NBLK, 256, 0, stream>>>(ei, flag, cnt_blk, E, chunk, NB);
    k_scan1<<<nb_s, 256, 0, stream>>>(cnt_blk, base_blk, partials, L);
    k_scan2<<<1, 1024, 0, stream>>>(partials, nb_s);
    k_scan3<<<nb_s, 256, 0, stream>>>(base_blk, partials, L);
    k_bin<<<NBLK, 256, 0, stream>>>(ei, flag, base_blk, epk, E, chunk, NB);
    k_csr<<<NB, 256, 0, stream>>>(epk, base_blk, csr, row_off, degi, dinv, n);

    int nb_g = (n + 3) / 4;   // one wave per node, 4 waves/block
    // layer 1 transform
    k_lin1<<<nb_n, 256, 0, stream>>>(x, W1, dinv, bufA, n);
    // gather1 + fused lin2:  bufA -> bufB
    k_gatherF<1><<<nb_g, 256, 0, stream>>>(csr, row_off, degi, dinv, bufA, W2, b1,
                                           bufB, n);
    // gather2 + fused lin3:  bufB -> bufA
    k_gatherF<1><<<nb_g, 256, 0, stream>>>(csr, row_off, degi, dinv, bufB, W3, b2,
                                           bufA, n);
    // gather3 (plain agg):   bufA -> bufB
    k_gatherF<0><<<nb_g, 256, 0, stream>>>(csr, row_off, degi, dinv, bufA, nullptr,
                                           nullptr, bufB, n);
    // MLP head (bf16 MFMA)
    k_mlp<<<(n + 63) / 64, 256, 0, stream>>>(x, bufB, b3, wl2t, bl2, wl3t, bl3,
                                             Wl4, bl4, out, n);
}